// Round 5
// baseline (5801.708 us; speedup 1.0000x reference)
//
#include <hip/hip_runtime.h>
#include <hip/hip_bf16.h>
#include <math.h>

typedef unsigned int uint32;
typedef _Float16 h2_t __attribute__((ext_vector_type(2)));

// Problem constants
static constexpr int NX = 32;    // state dim
static constexpr int NU = 8;     // control dim
static constexpr int NA = 24;    // obs dim
static constexpr int NH = 256;   // hidden
static constexpr int NT = 128;   // time steps
static constexpr int NB = 256;   // batch
static constexpr int NXP = NX + 1;   // padded row (bank-conflict fix)
static constexpr float MINV = 0.01f, MAXV = 1.0f, EPSV = 1e-6f;

// Padded head widths (outputs)
static constexpr int H1O = NX*NX + NX*NU + NX;   // 1312 real
static constexpr int H1P = 1344;                 // padded
static constexpr int H2O = NA*NX + NA;           // 792 real
static constexpr int H2P = 800;                  // padded

// Workspace layout in uint32 units (all 16B aligned)
static constexpr size_t OFF_W1 = 0;
static constexpr size_t OFF_W2 = 4096;
static constexpr size_t OFF_H1 = OFF_W2 + 32768;
static constexpr size_t OFF_H2 = OFF_H1 + 172032;
static constexpr size_t OFF_B1 = OFF_H2 + 102400;
static constexpr size_t OFF_B2 = OFF_B1 + 1344;

// ---------------------------------------------------------------------------
__global__ void pack_half_off(const float* __restrict__ src, uint32* __restrict__ dst,
                              int O, int K, int LDP, int off)
{
    int idx = blockIdx.x * blockDim.x + threadIdx.x;
    int K2 = K >> 1;
    if (idx >= O * K2) return;
    int kk = idx % K2;
    int o  = idx / K2;
    int k  = kk * 2;
    int k8 = k >> 3, q = (k >> 1) & 3;
    _Float16 a = (_Float16)src[o * K + k];
    _Float16 b = (_Float16)src[o * K + k + 1];
    uint32 val = (uint32)__builtin_bit_cast(unsigned short, a)
               | ((uint32)__builtin_bit_cast(unsigned short, b) << 16);
    dst[((size_t)k8 * LDP + off + o) * 4 + q] = val;
}

__global__ void pack_bias3(const float* __restrict__ s0, int n0,
                           const float* __restrict__ s1, int n1,
                           const float* __restrict__ s2, int n2,
                           float* __restrict__ dst)
{
    int i = blockIdx.x * blockDim.x + threadIdx.x;
    if (i < n0) dst[i] = s0[i];
    else if (i < n0 + n1) dst[i] = s1[i - n0];
    else if (i < n0 + n1 + n2) dst[i] = s2[i - n0 - n1];
}

// ---------------------------------------------------------------------------
__device__ __forceinline__ float dot2(uint32 w, uint32 x, float acc)
{
#if __has_builtin(__builtin_amdgcn_fdot2)
    return __builtin_amdgcn_fdot2(__builtin_bit_cast(h2_t, w),
                                  __builtin_bit_cast(h2_t, x), acc, false);
#else
    h2_t a = __builtin_bit_cast(h2_t, w), b = __builtin_bit_cast(h2_t, x);
    return acc + (float)a[0] * (float)b[0] + (float)a[1] * (float)b[1];
#endif
}

__device__ __forceinline__ float dot8(uint4 w, uint4 x, float acc)
{
    acc = dot2(w.x, x.x, acc);
    acc = dot2(w.y, x.y, acc);
    acc = dot2(w.z, x.z, acc);
    acc = dot2(w.w, x.w, acc);
    return acc;
}

__device__ __forceinline__ void tri_decode(int p, int& l, int& i)
{
    int lo = (int)((sqrtf(8.f * (float)p + 1.f) - 1.f) * 0.5f);
    while ((lo + 1) * (lo + 2) / 2 <= p) lo++;
    while (lo * (lo + 1) / 2 > p) lo--;
    l = lo;
    i = p - lo * (lo + 1) / 2;
}

__device__ __forceinline__ float sigm_scaled(float z)
{
    return MINV + (MAXV - MINV) / (1.f + expf(-z));
}

__device__ __forceinline__ unsigned short f2h(float v)
{
    _Float16 h = (_Float16)v;
    return __builtin_bit_cast(unsigned short, h);
}

// pack per-thread fp32 value (consecutive tid pairs) into fp16x2 LDS word
__device__ __forceinline__ void pack1_to(int tid, float v, uint32* d)
{
    unsigned short us = f2h(v);
    int pi = __shfl_xor((int)us, 1);
    if ((tid & 1) == 0)
        d[tid >> 1] = (uint32)us | ((uint32)pi << 16);
}

// ---------------------------------------------------------------------------
// 1 batch element per block, 1024 threads (16 waves/CU) for memory-level
// parallelism on the L2 weight stream.
__global__ __launch_bounds__(1024) void kf_kernel(
    const float* __restrict__ u, const float* __restrict__ a,
    const uint32* __restrict__ wsu,
    const float* __restrict__ b1, const float* __restrict__ b2,
    const float* __restrict__ alpha_p,
    float* __restrict__ out)
{
    const int tid = threadIdx.x;
    const int b   = blockIdx.x;
    const float alpha = alpha_p[0];

    const uint4* W1h = (const uint4*)(wsu + OFF_W1);
    const uint4* W2h = (const uint4*)(wsu + OFF_W2);
    const uint4* H1h = (const uint4*)(wsu + OFF_H1);
    const uint4* H2h = (const uint4*)(wsu + OFF_H2);
    const float* BH1 = (const float*)(wsu + OFF_B1);
    const float* BH2 = (const float*)(wsu + OFF_B2);

    __shared__ alignas(16) uint32 s_h1h[NH / 2];
    __shared__ alignas(16) uint32 s_h2h[NH / 2];
    __shared__ alignas(16) uint32 s_qmh[NX / 2];
    __shared__ alignas(16) uint32 s_pmh[NX / 2];
    __shared__ float s_part[4][NH];
    __shared__ float s_Am[NX * NXP];
    __shared__ float s_Bm[NX * NU];
    __shared__ float s_nx[NX];
    __shared__ float s_C[NA * NXP];
    __shared__ float s_na[NA];
    __shared__ float s_qm[NX], s_qc[NX * NXP];
    __shared__ float s_pm[NX], s_pc[NX * NXP];
    __shared__ float s_T2[NX * NXP];
    __shared__ float s_T1[NA * NXP];
    __shared__ float s_S[NA * NA];
    __shared__ float s_Y[NA * NX];
    __shared__ float s_innov[NA];
    __shared__ float s_a[NA], s_u[NU];

    const size_t pmO = 0;
    const size_t pcO = (size_t)NT * NB * NX;
    const size_t qmO = pcO + (size_t)NT * NB * NX * NX;
    const size_t qcO = qmO + (size_t)NT * NB * NX;

    for (int t = 0; t < NT; ++t) {
        const size_t mIdx = (size_t)t * NB + b;

        if (t == 0) {
            if (tid < NX) s_pm[tid] = 0.f;
            if (tid < NX / 2) s_pmh[tid] = 0u;
            if (tid < NX * NX) {
                int i = tid >> 5, l = tid & 31;
                s_pc[i * NXP + l] = (i == l) ? 1.f : 0.f;
            }
            __syncthreads();
        } else {
            // ===== A1: trunk-W1 on qm || store prev qm/qc, load u[t-1] =====
            if (tid < NH) {
                const uint4* xh = (const uint4*)s_qmh;
                float acc = b1[tid];
                #pragma unroll
                for (int k8 = 0; k8 < 4; k8++)
                    acc = dot8(W1h[k8 * NH + tid], xh[k8], acc);
                pack1_to(tid, fmaxf(acc, 0.f), s_h1h);
            } else {
                const size_t mPrev = (size_t)(t - 1) * NB + b;
                for (int s = tid - 256; s < NX + NX * NX; s += 768) {
                    if (s < NX)
                        __builtin_nontemporal_store(s_qm[s], out + qmO + mPrev * NX + s);
                    else {
                        int o = s - NX, i = o >> 5, l = o & 31;
                        __builtin_nontemporal_store(s_qc[i * NXP + l],
                                                    out + qcO + mPrev * NX * NX + o);
                    }
                }
                if (tid - 256 < NU)
                    s_u[tid - 256] = u[((size_t)(t - 1) * NB + b) * NU + (tid - 256)];
            }
            __syncthreads();

            // ===== A2: trunk-W2 split-K x4 =====
            {
                int o = tid & 255, g = tid >> 8;
                const uint4* xh = (const uint4*)s_h1h;
                float acc = 0.f;
                #pragma unroll 8
                for (int k8 = g * 8; k8 < g * 8 + 8; k8++)
                    acc = dot8(W2h[k8 * NH + o], xh[k8], acc);
                s_part[g][o] = acc;
            }
            __syncthreads();

            // ===== A3: h2 reduce + relu + pack =====
            if (tid < NH) {
                float v = fmaxf(s_part[0][tid] + s_part[1][tid] +
                                s_part[2][tid] + s_part[3][tid] + b2[tid], 0.f);
                pack1_to(tid, v, s_h2h);
            }
            __syncthreads();

            // ===== A4: head1 (Am | Bm | nx), 1312 outputs over 1024 lanes =====
            {
                const uint4* xh = (const uint4*)s_h2h;
                int o0 = tid, o1 = tid + 1024;
                float a0 = BH1[o0];
                float a1 = (tid < H1O - 1024) ? BH1[o1] : 0.f;
                #pragma unroll 8
                for (int k8 = 0; k8 < 32; k8++) {
                    uint4 x = xh[k8];
                    a0 = dot8(H1h[k8 * H1P + o0], x, a0);
                    if (tid < H1O - 1024) a1 = dot8(H1h[k8 * H1P + o1], x, a1);
                }
                // o0 in [0,1024) = Am region exactly
                {
                    int i = o0 >> 5, l = o0 & 31;
                    s_Am[i * NXP + l] = ((i == l) ? 1.f : 0.f) + alpha * a0;
                }
                if (tid < H1O - 1024) {
                    if (o1 < NX * NX + NX * NU) s_Bm[o1 - NX * NX] = a1;
                    else s_nx[o1 - (NX * NX + NX * NU)] = sigm_scaled(a1);
                }
            }
            __syncthreads();

            // ===== A5: T2 = Am@qc ; pm = Am@qm + Bm@u =====
            {
                int i = tid >> 5, l = tid & 31;
                float acc = 0.f;
                #pragma unroll
                for (int j = 0; j < NX; j++)
                    acc = fmaf(s_Am[i * NXP + j], s_qc[j * NXP + l], acc);
                s_T2[i * NXP + l] = acc;
            }
            if (tid < NX) {
                float acc = 0.f;
                #pragma unroll
                for (int j = 0; j < NX; j++) acc = fmaf(s_Am[tid * NXP + j], s_qm[j], acc);
                #pragma unroll
                for (int j = 0; j < NU; j++) acc = fmaf(s_Bm[tid * NU + j], s_u[j], acc);
                s_pm[tid] = acc;
                pack1_to(tid, acc, s_pmh);
            }
            __syncthreads();

            // ===== A6: pc = psd(T2 @ Am^T + diag(nx)) — 528 items =====
            if (tid < NX * (NX + 1) / 2) {
                int l, i; tri_decode(tid, l, i);
                float a_il = 0.f, a_li = 0.f;
                #pragma unroll
                for (int j = 0; j < NX; j++) {
                    a_il = fmaf(s_T2[i * NXP + j], s_Am[l * NXP + j], a_il);
                    a_li = fmaf(s_T2[l * NXP + j], s_Am[i * NXP + j], a_li);
                }
                if (i == l) {
                    s_pc[i * NXP + i] = a_il + s_nx[i] + EPSV;
                } else {
                    float v = 0.5f * (a_il + a_li);
                    s_pc[i * NXP + l] = v;
                    s_pc[l * NXP + i] = v;
                }
            }
            __syncthreads();
        }

        // ===== B1: trunk-W1 on pm || store pm/pc, load a[t] =====
        if (tid < NH) {
            const uint4* xh = (const uint4*)s_pmh;
            float acc = b1[tid];
            #pragma unroll
            for (int k8 = 0; k8 < 4; k8++)
                acc = dot8(W1h[k8 * NH + tid], xh[k8], acc);
            pack1_to(tid, fmaxf(acc, 0.f), s_h1h);
        } else {
            for (int s = tid - 256; s < NX + NX * NX; s += 768) {
                if (s < NX)
                    __builtin_nontemporal_store(s_pm[s], out + pmO + mIdx * NX + s);
                else {
                    int o = s - NX, i = o >> 5, l = o & 31;
                    __builtin_nontemporal_store(s_pc[i * NXP + l],
                                                out + pcO + mIdx * NX * NX + o);
                }
            }
            if (tid - 256 < NA)
                s_a[tid - 256] = a[mIdx * NA + (tid - 256)];
        }
        __syncthreads();

        // ===== B2: trunk-W2 split-K x4 =====
        {
            int o = tid & 255, g = tid >> 8;
            const uint4* xh = (const uint4*)s_h1h;
            float acc = 0.f;
            #pragma unroll 8
            for (int k8 = g * 8; k8 < g * 8 + 8; k8++)
                acc = dot8(W2h[k8 * NH + o], xh[k8], acc);
            s_part[g][o] = acc;
        }
        __syncthreads();

        // ===== B3: h2 reduce + relu + pack =====
        if (tid < NH) {
            float v = fmaxf(s_part[0][tid] + s_part[1][tid] +
                            s_part[2][tid] + s_part[3][tid] + b2[tid], 0.f);
            pack1_to(tid, v, s_h2h);
        }
        __syncthreads();

        // ===== B4: head2 (C | na), 792 outputs, 1/lane =====
        if (tid < H2P) {
            const uint4* xh = (const uint4*)s_h2h;
            float acc = BH2[tid];
            #pragma unroll 8
            for (int k8 = 0; k8 < 32; k8++)
                acc = dot8(H2h[k8 * H2P + tid], xh[k8], acc);
            if (tid < NA * NX) {
                int i = tid >> 5, l = tid & 31;
                s_C[i * NXP + l] = acc;
            } else if (tid < H2O) {
                s_na[tid - NA * NX] = sigm_scaled(acc);
            }
        }
        __syncthreads();

        // ===== B5: T1 = C@pc ; innov = a - C@pm =====
        if (tid < NA * NX) {
            int i = tid >> 5, l = tid & 31;
            float acc = 0.f;
            #pragma unroll
            for (int k = 0; k < NX; k++)
                acc = fmaf(s_C[i * NXP + k], s_pc[k * NXP + l], acc);
            s_T1[i * NXP + l] = acc;
        }
        if (tid >= 1000) {
            int i = tid - 1000;
            float acc = s_a[i];
            #pragma unroll
            for (int j = 0; j < NX; j++)
                acc = fmaf(-s_C[i * NXP + j], s_pm[j], acc);
            s_innov[i] = acc;
        }
        __syncthreads();

        // ===== B6: S = T1 @ C^T + diag(na) — 300 items =====
        if (tid < NA * (NA + 1) / 2) {
            int l, i; tri_decode(tid, l, i);
            float acc = 0.f;
            #pragma unroll
            for (int j = 0; j < NX; j++)
                acc = fmaf(s_T1[i * NXP + j], s_C[l * NXP + j], acc);
            if (i == l) acc += s_na[i];
            s_S[i * NA + l] = acc;
            s_S[l * NA + i] = acc;
        }
        __syncthreads();

        // ===== B7: single-wave register Gauss-Jordan: Y = S^-1 T1 =====
        if (tid < 64) {
            const int j = tid;
            float r[NA];
            #pragma unroll
            for (int i = 0; i < NA; i++) {
                float v = 0.f;
                if (j < NA) v = s_S[i * NA + j];
                else if (j < NA + NX) v = s_T1[i * NXP + (j - NA)];
                r[i] = v;
            }
            #pragma unroll
            for (int k = 0; k < NA; k++) {
                float piv = __shfl(r[k], k);
                float ip = 1.0f / piv;
                r[k] *= ip;
                #pragma unroll
                for (int i = 0; i < NA; i++) {
                    if (i == k) continue;
                    float f = __shfl(r[i], k);
                    r[i] = fmaf(-f, r[k], r[i]);
                }
            }
            if (j >= NA && j < NA + NX) {
                #pragma unroll
                for (int i = 0; i < NA; i++) s_Y[i * NX + (j - NA)] = r[i];
            }
        }
        __syncthreads();

        // ===== B8: qm = pm + Y^T innov ; qc = psd(pc - Y^T T1) =====
        if (tid < NX) {
            float acc = s_pm[tid];
            #pragma unroll
            for (int i = 0; i < NA; i++)
                acc = fmaf(s_Y[i * NX + tid], s_innov[i], acc);
            s_qm[tid] = acc;
            pack1_to(tid, acc, s_qmh);
        }
        if (tid < NX * (NX + 1) / 2) {
            int l, i; tri_decode(tid, l, i);
            float t_il = 0.f, t_li = 0.f;
            #pragma unroll
            for (int q = 0; q < NA; q++) {
                t_il = fmaf(s_Y[q * NX + i], s_T1[q * NXP + l], t_il);
                t_li = fmaf(s_Y[q * NX + l], s_T1[q * NXP + i], t_li);
            }
            if (i == l) {
                s_qc[i * NXP + i] = s_pc[i * NXP + i] - t_il + EPSV;
            } else {
                float v = 0.5f * ((s_pc[i * NXP + l] - t_il) + (s_pc[l * NXP + i] - t_li));
                s_qc[i * NXP + l] = v;
                s_qc[l * NXP + i] = v;
            }
        }
        __syncthreads();
    }

    // Epilogue: store final qm/qc (t = NT-1)
    {
        const size_t mLast = (size_t)(NT - 1) * NB + b;
        for (int s = tid; s < NX + NX * NX; s += 1024) {
            if (s < NX)
                __builtin_nontemporal_store(s_qm[s], out + qmO + mLast * NX + s);
            else {
                int o = s - NX, i = o >> 5, l = o & 31;
                __builtin_nontemporal_store(s_qc[i * NXP + l],
                                            out + qcO + mLast * NX * NX + o);
            }
        }
    }
}

// ---------------------------------------------------------------------------
extern "C" void kernel_launch(void* const* d_in, const int* in_sizes, int n_in,
                              void* d_out, int out_size, void* d_ws, size_t ws_size,
                              hipStream_t stream)
{
    const float* u    = (const float*)d_in[0];
    const float* a    = (const float*)d_in[1];
    const float* W1   = (const float*)d_in[2];
    const float* b1   = (const float*)d_in[3];
    const float* W2   = (const float*)d_in[4];
    const float* b2   = (const float*)d_in[5];
    const float* WA   = (const float*)d_in[6];
    const float* bA   = (const float*)d_in[7];
    const float* WB   = (const float*)d_in[8];
    const float* bB   = (const float*)d_in[9];
    const float* WC   = (const float*)d_in[10];
    const float* bC   = (const float*)d_in[11];
    const float* Wnx  = (const float*)d_in[12];
    const float* bnx  = (const float*)d_in[13];
    const float* Wna  = (const float*)d_in[14];
    const float* bna  = (const float*)d_in[15];
    const float* alph = (const float*)d_in[16];

    uint32* wsu = (uint32*)d_ws;
    float* out = (float*)d_out;

    auto pk = [&](const float* src, int O, int K, size_t dst_off, int LDP, int off) {
        int n = O * (K / 2);
        pack_half_off<<<(n + 255) / 256, 256, 0, stream>>>(src, wsu + dst_off, O, K, LDP, off);
    };
    pk(W1,  NH,      NX, OFF_W1, NH,  0);
    pk(W2,  NH,      NH, OFF_W2, NH,  0);
    pk(WA,  NX * NX, NH, OFF_H1, H1P, 0);
    pk(WB,  NX * NU, NH, OFF_H1, H1P, NX * NX);
    pk(Wnx, NX,      NH, OFF_H1, H1P, NX * NX + NX * NU);
    pk(WC,  NA * NX, NH, OFF_H2, H2P, 0);
    pk(Wna, NA,      NH, OFF_H2, H2P, NA * NX);

    pack_bias3<<<(H1O + 255) / 256, 256, 0, stream>>>(bA, NX * NX, bB, NX * NU, bnx, NX,
                                                      (float*)(wsu + OFF_B1));
    pack_bias3<<<(H2O + 255) / 256, 256, 0, stream>>>(bC, NA * NX, bna, NA, nullptr, 0,
                                                      (float*)(wsu + OFF_B2));

    kf_kernel<<<NB, 1024, 0, stream>>>(u, a, wsu, b1, b2, alph, out);
}

// Round 6
// 4126.650 us; speedup vs baseline: 1.4059x; 1.4059x over previous
//
#include <hip/hip_runtime.h>
#include <hip/hip_bf16.h>
#include <math.h>

typedef unsigned int uint32;
typedef _Float16 h2_t __attribute__((ext_vector_type(2)));

// Problem constants
static constexpr int NX = 32;    // state dim
static constexpr int NU = 8;     // control dim
static constexpr int NA = 24;    // obs dim
static constexpr int NH = 256;   // hidden
static constexpr int NT = 128;   // time steps
static constexpr int NB = 256;   // batch
static constexpr int NXP = NX + 1;   // padded row (bank-conflict fix, proven R4)
static constexpr float MINV = 0.01f, MAXV = 1.0f, EPSV = 1e-6f;

// Padded head widths (outputs)
static constexpr int H1O = NX*NX + NX*NU + NX;   // 1312 real
static constexpr int H1P = 1344;                 // padded
static constexpr int H2O = NA*NX + NA;           // 792 real
static constexpr int H2P = 800;                  // padded

// Workspace layout in uint32 units (all 16B aligned)
static constexpr size_t OFF_W1 = 0;
static constexpr size_t OFF_W2 = 4096;
static constexpr size_t OFF_H1 = OFF_W2 + 32768;
static constexpr size_t OFF_H2 = OFF_H1 + 172032;
static constexpr size_t OFF_B1 = OFF_H2 + 102400;
static constexpr size_t OFF_B2 = OFF_B1 + 1344;

// ---------------------------------------------------------------------------
__global__ void pack_half_off(const float* __restrict__ src, uint32* __restrict__ dst,
                              int O, int K, int LDP, int off)
{
    int idx = blockIdx.x * blockDim.x + threadIdx.x;
    int K2 = K >> 1;
    if (idx >= O * K2) return;
    int kk = idx % K2;
    int o  = idx / K2;
    int k  = kk * 2;
    int k8 = k >> 3, q = (k >> 1) & 3;
    _Float16 a = (_Float16)src[o * K + k];
    _Float16 b = (_Float16)src[o * K + k + 1];
    uint32 val = (uint32)__builtin_bit_cast(unsigned short, a)
               | ((uint32)__builtin_bit_cast(unsigned short, b) << 16);
    dst[((size_t)k8 * LDP + off + o) * 4 + q] = val;
}

__global__ void pack_bias3(const float* __restrict__ s0, int n0,
                           const float* __restrict__ s1, int n1,
                           const float* __restrict__ s2, int n2,
                           float* __restrict__ dst)
{
    int i = blockIdx.x * blockDim.x + threadIdx.x;
    if (i < n0) dst[i] = s0[i];
    else if (i < n0 + n1) dst[i] = s1[i - n0];
    else if (i < n0 + n1 + n2) dst[i] = s2[i - n0 - n1];
}

// ---------------------------------------------------------------------------
__device__ __forceinline__ float dot2(uint32 w, uint32 x, float acc)
{
#if __has_builtin(__builtin_amdgcn_fdot2)
    return __builtin_amdgcn_fdot2(__builtin_bit_cast(h2_t, w),
                                  __builtin_bit_cast(h2_t, x), acc, false);
#else
    h2_t a = __builtin_bit_cast(h2_t, w), b = __builtin_bit_cast(h2_t, x);
    return acc + (float)a[0] * (float)b[0] + (float)a[1] * (float)b[1];
#endif
}

__device__ __forceinline__ float dot8(uint4 w, uint4 x, float acc)
{
    acc = dot2(w.x, x.x, acc);
    acc = dot2(w.y, x.y, acc);
    acc = dot2(w.z, x.z, acc);
    acc = dot2(w.w, x.w, acc);
    return acc;
}

__device__ __forceinline__ void tri_decode(int p, int& l, int& i)
{
    int lo = (int)((sqrtf(8.f * (float)p + 1.f) - 1.f) * 0.5f);
    while ((lo + 1) * (lo + 2) / 2 <= p) lo++;
    while (lo * (lo + 1) / 2 > p) lo--;
    l = lo;
    i = p - lo * (lo + 1) / 2;
}

__device__ __forceinline__ float sigm_scaled(float z)
{
    return MINV + (MAXV - MINV) / (1.f + expf(-z));
}

__device__ __forceinline__ unsigned short f2h(float v)
{
    _Float16 h = (_Float16)v;
    return __builtin_bit_cast(unsigned short, h);
}

__device__ __forceinline__ void pack1_to(int tid, float v, uint32* d)
{
    unsigned short us = f2h(v);
    int pi = __shfl_xor((int)us, 1);
    if ((tid & 1) == 0)
        d[tid >> 1] = (uint32)us | ((uint32)pi << 16);
}

// ---------------------------------------------------------------------------
// 1 batch element per block, 512 threads (R3 shape — L2-resident weights),
// + padding + phase fusion + producer-side fire-and-forget stores.
__global__ __launch_bounds__(512) void kf_kernel(
    const float* __restrict__ u, const float* __restrict__ a,
    const uint32* __restrict__ wsu,
    const float* __restrict__ b1, const float* __restrict__ b2,
    const float* __restrict__ alpha_p,
    float* __restrict__ out)
{
    const int tid = threadIdx.x;
    const int b   = blockIdx.x;
    const float alpha = alpha_p[0];

    const uint4* W1h = (const uint4*)(wsu + OFF_W1);
    const uint4* W2h = (const uint4*)(wsu + OFF_W2);
    const uint4* H1h = (const uint4*)(wsu + OFF_H1);
    const uint4* H2h = (const uint4*)(wsu + OFF_H2);
    const float* BH1 = (const float*)(wsu + OFF_B1);
    const float* BH2 = (const float*)(wsu + OFF_B2);

    __shared__ alignas(16) uint32 s_h1h[NH / 2];
    __shared__ alignas(16) uint32 s_h2h[NH / 2];
    __shared__ alignas(16) uint32 s_qmh[NX / 2];
    __shared__ alignas(16) uint32 s_pmh[NX / 2];
    __shared__ float s_part[2][NH];
    __shared__ float s_Am[NX * NXP];
    __shared__ float s_Bm[NX * NU];
    __shared__ float s_nx[NX];
    __shared__ float s_C[NA * NXP];
    __shared__ float s_na[NA];
    __shared__ float s_qm[NX], s_qc[NX * NXP];
    __shared__ float s_pm[NX], s_pc[NX * NXP];
    __shared__ float s_T2[NX * NXP];
    __shared__ float s_T1[NA * NXP];
    __shared__ float s_S[NA * NA];
    __shared__ float s_Y[NA * NX];
    __shared__ float s_innov[NA];
    __shared__ float s_a[NA], s_u[NU];

    const size_t pmO = 0;
    const size_t pcO = (size_t)NT * NB * NX;
    const size_t qmO = pcO + (size_t)NT * NB * NX * NX;
    const size_t qcO = qmO + (size_t)NT * NB * NX;

    // Hoisted triangular index assignments (constant over t):
    // lanes 256-511 own the 528-item symmetric 32x32 phases (qc-finalize, pc-psd)
    int iA0 = 0, lA0 = 0, iA1 = 0, lA1 = 0, iA2 = 0, lA2 = 0, nA = 0;
    if (tid >= 256) {
        int s = tid - 256;
        tri_decode(s, lA0, iA0);
        tri_decode(s + 256, lA1, iA1);
        nA = 2;
        if (s < 16) { tri_decode(s + 512, lA2, iA2); nA = 3; }
    }
    // all lanes < 300 own one item of the 24x24 S build
    int iS = 0, lS = 0;
    if (tid < 300) tri_decode(tid, lS, iS);

    for (int t = 0; t < NT; ++t) {
        const size_t mIdx = (size_t)t * NB + b;

        if (t == 0) {
            // INIT: pm0 = 0, pc0 = I; store pm0
            if (tid < NX) {
                s_pm[tid] = 0.f;
                __builtin_nontemporal_store(0.f, out + pmO + mIdx * NX + tid);
            }
            if (tid < NX / 2) s_pmh[tid] = 0u;
            #pragma unroll
            for (int r = 0; r < 2; r++) {
                int o = tid + 512 * r, i = o >> 5, l = o & 31;
                s_pc[i * NXP + l] = (i == l) ? 1.f : 0.f;
            }
            __syncthreads();
        } else {
            // ===== P1 [fused]: lanes<256: W1@qm -> h1 ; lanes>=256: finalize
            //       qc[t-1] from (Y,T1,pc of prev step), store it; load u[t-1].
            if (tid < NH) {
                const uint4* xh = (const uint4*)s_qmh;
                float acc = b1[tid];
                #pragma unroll
                for (int k8 = 0; k8 < 4; k8++)
                    acc = dot8(W1h[k8 * NH + tid], xh[k8], acc);
                pack1_to(tid, fmaxf(acc, 0.f), s_h1h);
            } else {
                const size_t mPrev = (size_t)(t - 1) * NB + b;
                float* outq = out + qcO + mPrev * NX * NX;
                #pragma unroll
                for (int k = 0; k < 3; k++) {
                    if (k >= nA) break;
                    int i = (k == 0) ? iA0 : (k == 1) ? iA1 : iA2;
                    int l = (k == 0) ? lA0 : (k == 1) ? lA1 : lA2;
                    float t_il = 0.f, t_li = 0.f;
                    #pragma unroll
                    for (int q = 0; q < NA; q++) {
                        t_il = fmaf(s_Y[q * NX + i], s_T1[q * NXP + l], t_il);
                        t_li = fmaf(s_Y[q * NX + l], s_T1[q * NXP + i], t_li);
                    }
                    if (i == l) {
                        float v = s_pc[i * NXP + i] - t_il + EPSV;
                        s_qc[i * NXP + i] = v;
                        __builtin_nontemporal_store(v, outq + i * NX + i);
                    } else {
                        float v = 0.5f * ((s_pc[i * NXP + l] - t_il) + (s_pc[l * NXP + i] - t_li));
                        s_qc[i * NXP + l] = v;
                        s_qc[l * NXP + i] = v;
                        __builtin_nontemporal_store(v, outq + i * NX + l);
                        __builtin_nontemporal_store(v, outq + l * NX + i);
                    }
                }
                int s = tid - 256;
                if (s < NU) s_u[s] = u[mPrev * NU + s];
            }
            __syncthreads();

            // ===== P2: trunk-W2 split-K =====
            {
                int o = tid & 255, g = tid >> 8;
                const uint4* xh = (const uint4*)s_h1h;
                float acc = 0.f;
                #pragma unroll 4
                for (int k8 = g * 16; k8 < g * 16 + 16; k8++)
                    acc = dot8(W2h[k8 * NH + o], xh[k8], acc);
                s_part[g][o] = acc;
            }
            __syncthreads();

            // ===== P3: h2 reduce + relu + pack =====
            if (tid < NH) {
                float v = fmaxf(s_part[0][tid] + s_part[1][tid] + b2[tid], 0.f);
                pack1_to(tid, v, s_h2h);
            }
            __syncthreads();

            // ===== P4: head1 (Am | Bm | nx) =====
            {
                const uint4* xh = (const uint4*)s_h2h;
                int o0 = tid, o1 = tid + 512, o2 = tid + 1024;
                float a0 = BH1[o0], a1 = BH1[o1];
                float a2 = (tid < 320) ? BH1[o2] : 0.f;
                #pragma unroll 8
                for (int k8 = 0; k8 < 32; k8++) {
                    uint4 x = xh[k8];
                    a0 = dot8(H1h[k8 * H1P + o0], x, a0);
                    a1 = dot8(H1h[k8 * H1P + o1], x, a1);
                    if (tid < 320) a2 = dot8(H1h[k8 * H1P + o2], x, a2);
                }
                {
                    int i = o0 >> 5, l = o0 & 31;
                    s_Am[i * NXP + l] = ((i == l) ? 1.f : 0.f) + alpha * a0;
                }
                {
                    int i = o1 >> 5, l = o1 & 31;
                    s_Am[i * NXP + l] = ((i == l) ? 1.f : 0.f) + alpha * a1;
                }
                if (tid < 320) {
                    if (o2 < NX * NX + NX * NU) s_Bm[o2 - NX * NX] = a2;
                    else if (o2 < H1O) s_nx[o2 - (NX * NX + NX * NU)] = sigm_scaled(a2);
                }
            }
            __syncthreads();

            // ===== P5: T2 = Am@qc ; pm = Am@qm + Bm@u (+pack, +store) =====
            #pragma unroll
            for (int r = 0; r < 2; r++) {
                int o = tid + 512 * r, i = o >> 5, l = o & 31;
                float acc = 0.f;
                #pragma unroll
                for (int j = 0; j < NX; j++)
                    acc = fmaf(s_Am[i * NXP + j], s_qc[j * NXP + l], acc);
                s_T2[i * NXP + l] = acc;
            }
            if (tid < NX) {
                float acc = 0.f;
                #pragma unroll
                for (int j = 0; j < NX; j++) acc = fmaf(s_Am[tid * NXP + j], s_qm[j], acc);
                #pragma unroll
                for (int j = 0; j < NU; j++) acc = fmaf(s_Bm[tid * NU + j], s_u[j], acc);
                s_pm[tid] = acc;
                pack1_to(tid, acc, s_pmh);
                __builtin_nontemporal_store(acc, out + pmO + mIdx * NX + tid);
            }
            __syncthreads();
        }

        // ===== P6 [fused]: lanes<256: W1@pm -> h1 ; lanes>=256: pc-psd
        //       (t>0) or pass-through (t==0), store pc[t]; load a[t].
        if (tid < NH) {
            const uint4* xh = (const uint4*)s_pmh;
            float acc = b1[tid];
            #pragma unroll
            for (int k8 = 0; k8 < 4; k8++)
                acc = dot8(W1h[k8 * NH + tid], xh[k8], acc);
            pack1_to(tid, fmaxf(acc, 0.f), s_h1h);
        } else {
            float* outp = out + pcO + mIdx * NX * NX;
            #pragma unroll
            for (int k = 0; k < 3; k++) {
                if (k >= nA) break;
                int i = (k == 0) ? iA0 : (k == 1) ? iA1 : iA2;
                int l = (k == 0) ? lA0 : (k == 1) ? lA1 : lA2;
                if (t > 0) {
                    float a_il = 0.f, a_li = 0.f;
                    #pragma unroll
                    for (int j = 0; j < NX; j++) {
                        a_il = fmaf(s_T2[i * NXP + j], s_Am[l * NXP + j], a_il);
                        a_li = fmaf(s_T2[l * NXP + j], s_Am[i * NXP + j], a_li);
                    }
                    if (i == l) {
                        float v = a_il + s_nx[i] + EPSV;
                        s_pc[i * NXP + i] = v;
                        __builtin_nontemporal_store(v, outp + i * NX + i);
                    } else {
                        float v = 0.5f * (a_il + a_li);
                        s_pc[i * NXP + l] = v;
                        s_pc[l * NXP + i] = v;
                        __builtin_nontemporal_store(v, outp + i * NX + l);
                        __builtin_nontemporal_store(v, outp + l * NX + i);
                    }
                } else {
                    float v = (i == l) ? 1.f : 0.f;
                    __builtin_nontemporal_store(v, outp + i * NX + l);
                    if (i != l) __builtin_nontemporal_store(v, outp + l * NX + i);
                }
            }
            int s = tid - 256;
            if (s >= 232) s_a[s - 232] = a[mIdx * NA + (s - 232)];
        }
        __syncthreads();

        // ===== P7: trunk-W2 split-K =====
        {
            int o = tid & 255, g = tid >> 8;
            const uint4* xh = (const uint4*)s_h1h;
            float acc = 0.f;
            #pragma unroll 4
            for (int k8 = g * 16; k8 < g * 16 + 16; k8++)
                acc = dot8(W2h[k8 * NH + o], xh[k8], acc);
            s_part[g][o] = acc;
        }
        __syncthreads();

        // ===== P8: h2 reduce + relu + pack =====
        if (tid < NH) {
            float v = fmaxf(s_part[0][tid] + s_part[1][tid] + b2[tid], 0.f);
            pack1_to(tid, v, s_h2h);
        }
        __syncthreads();

        // ===== P9: head2 (C | na) =====
        {
            const uint4* xh = (const uint4*)s_h2h;
            int o0 = tid, o1 = tid + 512;
            float a0 = BH2[o0];
            float a1 = (tid < H2P - 512) ? BH2[o1] : 0.f;
            #pragma unroll 8
            for (int k8 = 0; k8 < 32; k8++) {
                uint4 x = xh[k8];
                a0 = dot8(H2h[k8 * H2P + o0], x, a0);
                if (tid < H2P - 512) a1 = dot8(H2h[k8 * H2P + o1], x, a1);
            }
            {
                int i = o0 >> 5, l = o0 & 31;
                s_C[i * NXP + l] = a0;   // o0 < 512 always in C region
            }
            if (tid < H2P - 512) {
                if (o1 < NA * NX) {
                    int i = o1 >> 5, l = o1 & 31;
                    s_C[i * NXP + l] = a1;
                } else if (o1 < H2O) {
                    s_na[o1 - NA * NX] = sigm_scaled(a1);
                }
            }
        }
        __syncthreads();

        // ===== P10: T1 = C@pc ; innov = a - C@pm =====
        {
            int p = tid;
            {
                int i = p >> 5, l = p & 31;
                float acc = 0.f;
                #pragma unroll
                for (int k = 0; k < NX; k++)
                    acc = fmaf(s_C[i * NXP + k], s_pc[k * NXP + l], acc);
                s_T1[i * NXP + l] = acc;
            }
            int p2 = tid + 512;
            if (p2 < NA * NX) {
                int i = p2 >> 5, l = p2 & 31;
                float acc = 0.f;
                #pragma unroll
                for (int k = 0; k < NX; k++)
                    acc = fmaf(s_C[i * NXP + k], s_pc[k * NXP + l], acc);
                s_T1[i * NXP + l] = acc;
            }
            if (tid >= 488) {
                int i = tid - 488;
                float acc = s_a[i];
                #pragma unroll
                for (int j = 0; j < NX; j++)
                    acc = fmaf(-s_C[i * NXP + j], s_pm[j], acc);
                s_innov[i] = acc;
            }
        }
        __syncthreads();

        // ===== P11: S = T1 @ C^T + diag(na) =====
        if (tid < NA * (NA + 1) / 2) {
            float acc = 0.f;
            #pragma unroll
            for (int j = 0; j < NX; j++)
                acc = fmaf(s_T1[iS * NXP + j], s_C[lS * NXP + j], acc);
            if (iS == lS) acc += s_na[iS];
            s_S[iS * NA + lS] = acc;
            s_S[lS * NA + iS] = acc;
        }
        __syncthreads();

        // ===== P12: wave-0 register Gauss-Jordan + qm tail (+store qm) =====
        if (tid < 64) {
            const int j = tid;
            float r[NA];
            #pragma unroll
            for (int i = 0; i < NA; i++) {
                float v = 0.f;
                if (j < NA) v = s_S[i * NA + j];
                else if (j < NA + NX) v = s_T1[i * NXP + (j - NA)];
                r[i] = v;
            }
            #pragma unroll
            for (int k = 0; k < NA; k++) {
                float piv = __shfl(r[k], k);
                float ip = 1.0f / piv;
                r[k] *= ip;
                #pragma unroll
                for (int i = 0; i < NA; i++) {
                    if (i == k) continue;
                    float f = __shfl(r[i], k);
                    r[i] = fmaf(-f, r[k], r[i]);
                }
            }
            if (j >= NA && j < NA + NX) {
                int x = j - NA;
                float acc = s_pm[x];
                #pragma unroll
                for (int i = 0; i < NA; i++) {
                    s_Y[i * NX + x] = r[i];
                    acc = fmaf(r[i], s_innov[i], acc);
                }
                s_qm[x] = acc;
                // pack qmh: lanes 24..55, x parity == lane parity (24 even)
                unsigned short us = f2h(acc);
                int pi = __shfl_xor((int)us, 1);
                if ((x & 1) == 0)
                    s_qmh[x >> 1] = (uint32)us | ((uint32)pi << 16);
                __builtin_nontemporal_store(acc, out + qmO + mIdx * NX + x);
            }
        }
        __syncthreads();
    }

    // Epilogue: finalize + store qc[NT-1] (from last Y, T1, pc)
    if (tid >= 256) {
        const size_t mLast = (size_t)(NT - 1) * NB + b;
        float* outq = out + qcO + mLast * NX * NX;
        #pragma unroll
        for (int k = 0; k < 3; k++) {
            if (k >= nA) break;
            int i = (k == 0) ? iA0 : (k == 1) ? iA1 : iA2;
            int l = (k == 0) ? lA0 : (k == 1) ? lA1 : lA2;
            float t_il = 0.f, t_li = 0.f;
            #pragma unroll
            for (int q = 0; q < NA; q++) {
                t_il = fmaf(s_Y[q * NX + i], s_T1[q * NXP + l], t_il);
                t_li = fmaf(s_Y[q * NX + l], s_T1[q * NXP + i], t_li);
            }
            if (i == l) {
                __builtin_nontemporal_store(s_pc[i * NXP + i] - t_il + EPSV,
                                            outq + i * NX + i);
            } else {
                float v = 0.5f * ((s_pc[i * NXP + l] - t_il) + (s_pc[l * NXP + i] - t_li));
                __builtin_nontemporal_store(v, outq + i * NX + l);
                __builtin_nontemporal_store(v, outq + l * NX + i);
            }
        }
    }
}

// ---------------------------------------------------------------------------
extern "C" void kernel_launch(void* const* d_in, const int* in_sizes, int n_in,
                              void* d_out, int out_size, void* d_ws, size_t ws_size,
                              hipStream_t stream)
{
    const float* u    = (const float*)d_in[0];
    const float* a    = (const float*)d_in[1];
    const float* W1   = (const float*)d_in[2];
    const float* b1   = (const float*)d_in[3];
    const float* W2   = (const float*)d_in[4];
    const float* b2   = (const float*)d_in[5];
    const float* WA   = (const float*)d_in[6];
    const float* bA   = (const float*)d_in[7];
    const float* WB   = (const float*)d_in[8];
    const float* bB   = (const float*)d_in[9];
    const float* WC   = (const float*)d_in[10];
    const float* bC   = (const float*)d_in[11];
    const float* Wnx  = (const float*)d_in[12];
    const float* bnx  = (const float*)d_in[13];
    const float* Wna  = (const float*)d_in[14];
    const float* bna  = (const float*)d_in[15];
    const float* alph = (const float*)d_in[16];

    uint32* wsu = (uint32*)d_ws;
    float* out = (float*)d_out;

    auto pk = [&](const float* src, int O, int K, size_t dst_off, int LDP, int off) {
        int n = O * (K / 2);
        pack_half_off<<<(n + 255) / 256, 256, 0, stream>>>(src, wsu + dst_off, O, K, LDP, off);
    };
    pk(W1,  NH,      NX, OFF_W1, NH,  0);
    pk(W2,  NH,      NH, OFF_W2, NH,  0);
    pk(WA,  NX * NX, NH, OFF_H1, H1P, 0);
    pk(WB,  NX * NU, NH, OFF_H1, H1P, NX * NX);
    pk(Wnx, NX,      NH, OFF_H1, H1P, NX * NX + NX * NU);
    pk(WC,  NA * NX, NH, OFF_H2, H2P, 0);
    pk(Wna, NA,      NH, OFF_H2, H2P, NA * NX);

    pack_bias3<<<(H1O + 255) / 256, 256, 0, stream>>>(bA, NX * NX, bB, NX * NU, bnx, NX,
                                                      (float*)(wsu + OFF_B1));
    pack_bias3<<<(H2O + 255) / 256, 256, 0, stream>>>(bC, NA * NX, bna, NA, nullptr, 0,
                                                      (float*)(wsu + OFF_B2));

    kf_kernel<<<NB, 512, 0, stream>>>(u, a, wsu, b1, b2, alph, out);
}

// Round 7
// 3723.130 us; speedup vs baseline: 1.5583x; 1.1084x over previous
//
#include <hip/hip_runtime.h>
#include <hip/hip_bf16.h>
#include <math.h>

typedef unsigned int uint32;
typedef _Float16 h2_t __attribute__((ext_vector_type(2)));

// Problem constants
static constexpr int NX = 32;    // state dim
static constexpr int NU = 8;     // control dim
static constexpr int NA = 24;    // obs dim
static constexpr int NH = 256;   // hidden
static constexpr int NT = 128;   // time steps
static constexpr int NB = 256;   // batch
static constexpr int NXP = NX + 1;   // padded row (bank-conflict fix)
static constexpr float MINV = 0.01f, MAXV = 1.0f, EPSV = 1e-6f;

// Padded head widths (outputs)
static constexpr int H1O = NX*NX + NX*NU + NX;   // 1312 real
static constexpr int H1P = 1344;                 // padded
static constexpr int H2O = NA*NX + NA;           // 792 real
static constexpr int H2P = 800;                  // padded

// Workspace layout in uint32 units (all 16B aligned)
static constexpr size_t OFF_W1 = 0;
static constexpr size_t OFF_W2 = 4096;
static constexpr size_t OFF_H1 = OFF_W2 + 32768;
static constexpr size_t OFF_H2 = OFF_H1 + 172032;
static constexpr size_t OFF_B1 = OFF_H2 + 102400;
static constexpr size_t OFF_B2 = OFF_B1 + 1344;

// ---------------------------------------------------------------------------
__global__ void pack_half_off(const float* __restrict__ src, uint32* __restrict__ dst,
                              int O, int K, int LDP, int off)
{
    int idx = blockIdx.x * blockDim.x + threadIdx.x;
    int K2 = K >> 1;
    if (idx >= O * K2) return;
    int kk = idx % K2;
    int o  = idx / K2;
    int k  = kk * 2;
    int k8 = k >> 3, q = (k >> 1) & 3;
    _Float16 a = (_Float16)src[o * K + k];
    _Float16 b = (_Float16)src[o * K + k + 1];
    uint32 val = (uint32)__builtin_bit_cast(unsigned short, a)
               | ((uint32)__builtin_bit_cast(unsigned short, b) << 16);
    dst[((size_t)k8 * LDP + off + o) * 4 + q] = val;
}

__global__ void pack_bias3(const float* __restrict__ s0, int n0,
                           const float* __restrict__ s1, int n1,
                           const float* __restrict__ s2, int n2,
                           float* __restrict__ dst)
{
    int i = blockIdx.x * blockDim.x + threadIdx.x;
    if (i < n0) dst[i] = s0[i];
    else if (i < n0 + n1) dst[i] = s1[i - n0];
    else if (i < n0 + n1 + n2) dst[i] = s2[i - n0 - n1];
}

// ---------------------------------------------------------------------------
__device__ __forceinline__ float dot2(uint32 w, uint32 x, float acc)
{
#if __has_builtin(__builtin_amdgcn_fdot2)
    return __builtin_amdgcn_fdot2(__builtin_bit_cast(h2_t, w),
                                  __builtin_bit_cast(h2_t, x), acc, false);
#else
    h2_t a = __builtin_bit_cast(h2_t, w), b = __builtin_bit_cast(h2_t, x);
    return acc + (float)a[0] * (float)b[0] + (float)a[1] * (float)b[1];
#endif
}

__device__ __forceinline__ float dot8(uint4 w, uint4 x, float acc)
{
    acc = dot2(w.x, x.x, acc);
    acc = dot2(w.y, x.y, acc);
    acc = dot2(w.z, x.z, acc);
    acc = dot2(w.w, x.w, acc);
    return acc;
}

__device__ __forceinline__ void tri_decode(int p, int& l, int& i)
{
    int lo = (int)((sqrtf(8.f * (float)p + 1.f) - 1.f) * 0.5f);
    while ((lo + 1) * (lo + 2) / 2 <= p) lo++;
    while (lo * (lo + 1) / 2 > p) lo--;
    l = lo;
    i = p - lo * (lo + 1) / 2;
}

__device__ __forceinline__ float sigm_scaled(float z)
{
    return MINV + (MAXV - MINV) / (1.f + expf(-z));
}

__device__ __forceinline__ unsigned short f2h(float v)
{
    _Float16 h = (_Float16)v;
    return __builtin_bit_cast(unsigned short, h);
}

__device__ __forceinline__ void pack1_to(int tid, float v, uint32* d)
{
    unsigned short us = f2h(v);
    int pi = __shfl_xor((int)us, 1);
    if ((tid & 1) == 0)
        d[tid >> 1] = (uint32)us | ((uint32)pi << 16);
}

// ---------------------------------------------------------------------------
// 1 batch element per block, 1024 threads, 4 waves/SIMD.
// __launch_bounds__(1024, 4): VGPR cap = 512/4 = 128 — prevents the R5
// failure mode (compiler targeting 64 VGPR and spilling load batches).
__global__ __launch_bounds__(1024, 4) void kf_kernel(
    const float* __restrict__ u, const float* __restrict__ a,
    const uint32* __restrict__ wsu,
    const float* __restrict__ b1, const float* __restrict__ b2,
    const float* __restrict__ alpha_p,
    float* __restrict__ out)
{
    const int tid = threadIdx.x;
    const int b   = blockIdx.x;
    const float alpha = alpha_p[0];

    const uint4* W1h = (const uint4*)(wsu + OFF_W1);
    const uint4* W2h = (const uint4*)(wsu + OFF_W2);
    const uint4* H1h = (const uint4*)(wsu + OFF_H1);
    const uint4* H2h = (const uint4*)(wsu + OFF_H2);
    const float* BH1 = (const float*)(wsu + OFF_B1);
    const float* BH2 = (const float*)(wsu + OFF_B2);

    __shared__ alignas(16) uint32 s_h1h[NH / 2];
    __shared__ alignas(16) uint32 s_h2h[NH / 2];
    __shared__ alignas(16) uint32 s_qmh[NX / 2];
    __shared__ alignas(16) uint32 s_pmh[NX / 2];
    __shared__ float s_part[4][NH];
    __shared__ float s_Am[NX * NXP];
    __shared__ float s_Bm[NX * NU];
    __shared__ float s_nx[NX];
    __shared__ float s_C[NA * NXP];
    __shared__ float s_na[NA];
    __shared__ float s_qm[NX], s_qc[NX * NXP];
    __shared__ float s_pm[NX], s_pc[NX * NXP];
    __shared__ float s_T2[NX * NXP];
    __shared__ float s_T1[NA * NXP];
    __shared__ float s_S[NA * NA];
    __shared__ float s_Y[NA * NX];
    __shared__ float s_innov[NA];
    __shared__ float s_a[NA], s_u[NU];

    const size_t pmO = 0;
    const size_t pcO = (size_t)NT * NB * NX;
    const size_t qmO = pcO + (size_t)NT * NB * NX * NX;
    const size_t qcO = qmO + (size_t)NT * NB * NX;

    // Hoisted triangular index maps (constant over t)
    int iT = 0, lT = 0;                 // 528-item 32x32 triangle, tid<528
    if (tid < 528) tri_decode(tid, lT, iT);
    int iS = 0, lS = 0;                 // 300-item 24x24 triangle, tid<300
    if (tid < 300) tri_decode(tid, lS, iS);

    for (int t = 0; t < NT; ++t) {
        const size_t mIdx = (size_t)t * NB + b;

        if (t == 0) {
            if (tid < NX) s_pm[tid] = 0.f;
            if (tid < NX / 2) s_pmh[tid] = 0u;
            {
                int i = tid >> 5, l = tid & 31;
                s_pc[i * NXP + l] = (i == l) ? 1.f : 0.f;
            }
            __syncthreads();
        } else {
            // ===== A1: lanes<256: W1@qm -> h1 ; lanes>=256: store qm/qc[t-1]
            //       (coalesced), load u[t-1]. =====
            if (tid < NH) {
                const uint4* xh = (const uint4*)s_qmh;
                float acc = b1[tid];
                #pragma unroll
                for (int k8 = 0; k8 < 4; k8++)
                    acc = dot8(W1h[k8 * NH + tid], xh[k8], acc);
                pack1_to(tid, fmaxf(acc, 0.f), s_h1h);
            } else {
                const size_t mPrev = (size_t)(t - 1) * NB + b;
                for (int s = tid - 256; s < NX + NX * NX; s += 768) {
                    if (s < NX)
                        __builtin_nontemporal_store(s_qm[s], out + qmO + mPrev * NX + s);
                    else {
                        int o = s - NX, i = o >> 5, l = o & 31;
                        __builtin_nontemporal_store(s_qc[i * NXP + l],
                                                    out + qcO + mPrev * NX * NX + o);
                    }
                }
                if (tid >= 1016)
                    s_u[tid - 1016] = u[((size_t)(t - 1) * NB + b) * NU + (tid - 1016)];
            }
            __syncthreads();

            // ===== A2: trunk-W2 split-K x4 =====
            {
                int o = tid & 255, g = tid >> 8;
                const uint4* xh = (const uint4*)s_h1h;
                float acc = 0.f;
                #pragma unroll 4
                for (int k8 = g * 8; k8 < g * 8 + 8; k8++)
                    acc = dot8(W2h[k8 * NH + o], xh[k8], acc);
                s_part[g][o] = acc;
            }
            __syncthreads();

            // ===== A3: h2 reduce + relu + pack =====
            if (tid < NH) {
                float v = fmaxf(s_part[0][tid] + s_part[1][tid] +
                                s_part[2][tid] + s_part[3][tid] + b2[tid], 0.f);
                pack1_to(tid, v, s_h2h);
            }
            __syncthreads();

            // ===== A4: head1 — o0=tid covers Am exactly; 320 lanes carry Bm|nx =====
            {
                const uint4* xh = (const uint4*)s_h2h;
                int o0 = tid, o1 = tid + 1024;
                float a0 = BH1[o0];
                float a1 = (o1 < H1O) ? BH1[o1] : 0.f;
                #pragma unroll 4
                for (int k8 = 0; k8 < 32; k8++) {
                    uint4 x = xh[k8];
                    a0 = dot8(H1h[k8 * H1P + o0], x, a0);
                    if (o1 < H1O) a1 = dot8(H1h[k8 * H1P + o1], x, a1);
                }
                {
                    int i = o0 >> 5, l = o0 & 31;
                    s_Am[i * NXP + l] = ((i == l) ? 1.f : 0.f) + alpha * a0;
                }
                if (o1 < H1O) {
                    if (o1 < NX * NX + NX * NU) s_Bm[o1 - NX * NX] = a1;
                    else s_nx[o1 - (NX * NX + NX * NU)] = sigm_scaled(a1);
                }
            }
            __syncthreads();

            // ===== A5: T2 = Am@qc (1/lane) ; pm = Am@qm + Bm@u =====
            {
                int i = tid >> 5, l = tid & 31;
                float acc = 0.f;
                #pragma unroll
                for (int j = 0; j < NX; j++)
                    acc = fmaf(s_Am[i * NXP + j], s_qc[j * NXP + l], acc);
                s_T2[i * NXP + l] = acc;
            }
            if (tid < NX) {
                float acc = 0.f;
                #pragma unroll
                for (int j = 0; j < NX; j++) acc = fmaf(s_Am[tid * NXP + j], s_qm[j], acc);
                #pragma unroll
                for (int j = 0; j < NU; j++) acc = fmaf(s_Bm[tid * NU + j], s_u[j], acc);
                s_pm[tid] = acc;
                pack1_to(tid, acc, s_pmh);
            }
            __syncthreads();

            // ===== A6: pc = psd(T2 @ Am^T + diag(nx)) — 1/lane =====
            if (tid < 528) {
                int i = iT, l = lT;
                float a_il = 0.f, a_li = 0.f;
                #pragma unroll
                for (int j = 0; j < NX; j++) {
                    a_il = fmaf(s_T2[i * NXP + j], s_Am[l * NXP + j], a_il);
                    a_li = fmaf(s_T2[l * NXP + j], s_Am[i * NXP + j], a_li);
                }
                if (i == l) {
                    s_pc[i * NXP + i] = a_il + s_nx[i] + EPSV;
                } else {
                    float v = 0.5f * (a_il + a_li);
                    s_pc[i * NXP + l] = v;
                    s_pc[l * NXP + i] = v;
                }
            }
            __syncthreads();
        }

        // ===== B1: lanes<256: W1@pm -> h1 ; lanes>=256: store pm/pc[t]
        //       (coalesced), load a[t]. =====
        if (tid < NH) {
            const uint4* xh = (const uint4*)s_pmh;
            float acc = b1[tid];
            #pragma unroll
            for (int k8 = 0; k8 < 4; k8++)
                acc = dot8(W1h[k8 * NH + tid], xh[k8], acc);
            pack1_to(tid, fmaxf(acc, 0.f), s_h1h);
        } else {
            for (int s = tid - 256; s < NX + NX * NX; s += 768) {
                if (s < NX)
                    __builtin_nontemporal_store(s_pm[s], out + pmO + mIdx * NX + s);
                else {
                    int o = s - NX, i = o >> 5, l = o & 31;
                    __builtin_nontemporal_store(s_pc[i * NXP + l],
                                                out + pcO + mIdx * NX * NX + o);
                }
            }
            if (tid >= 1000)
                s_a[tid - 1000] = a[mIdx * NA + (tid - 1000)];
        }
        __syncthreads();

        // ===== B2: trunk-W2 split-K x4 =====
        {
            int o = tid & 255, g = tid >> 8;
            const uint4* xh = (const uint4*)s_h1h;
            float acc = 0.f;
            #pragma unroll 4
            for (int k8 = g * 8; k8 < g * 8 + 8; k8++)
                acc = dot8(W2h[k8 * NH + o], xh[k8], acc);
            s_part[g][o] = acc;
        }
        __syncthreads();

        // ===== B3: h2 reduce + relu + pack =====
        if (tid < NH) {
            float v = fmaxf(s_part[0][tid] + s_part[1][tid] +
                            s_part[2][tid] + s_part[3][tid] + b2[tid], 0.f);
            pack1_to(tid, v, s_h2h);
        }
        __syncthreads();

        // ===== B4: head2 (C | na), 1/lane =====
        if (tid < H2P) {
            const uint4* xh = (const uint4*)s_h2h;
            float acc = BH2[tid];
            #pragma unroll 4
            for (int k8 = 0; k8 < 32; k8++)
                acc = dot8(H2h[k8 * H2P + tid], xh[k8], acc);
            if (tid < NA * NX) {
                int i = tid >> 5, l = tid & 31;
                s_C[i * NXP + l] = acc;
            } else if (tid < H2O) {
                s_na[tid - NA * NX] = sigm_scaled(acc);
            }
        }
        __syncthreads();

        // ===== B5: T1 = C@pc (1/lane) ; innov = a - C@pm =====
        if (tid < NA * NX) {
            int i = tid >> 5, l = tid & 31;
            float acc = 0.f;
            #pragma unroll
            for (int k = 0; k < NX; k++)
                acc = fmaf(s_C[i * NXP + k], s_pc[k * NXP + l], acc);
            s_T1[i * NXP + l] = acc;
        }
        if (tid >= 1000) {
            int i = tid - 1000;
            float acc = s_a[i];
            #pragma unroll
            for (int j = 0; j < NX; j++)
                acc = fmaf(-s_C[i * NXP + j], s_pm[j], acc);
            s_innov[i] = acc;
        }
        __syncthreads();

        // ===== B6: S = T1 @ C^T + diag(na) — 1/lane =====
        if (tid < 300) {
            float acc = 0.f;
            #pragma unroll
            for (int j = 0; j < NX; j++)
                acc = fmaf(s_T1[iS * NXP + j], s_C[lS * NXP + j], acc);
            if (iS == lS) acc += s_na[iS];
            s_S[iS * NA + lS] = acc;
            s_S[lS * NA + iS] = acc;
        }
        __syncthreads();

        // ===== B7: single-wave register Gauss-Jordan: Y = S^-1 T1 =====
        if (tid < 64) {
            const int j = tid;
            float r[NA];
            #pragma unroll
            for (int i = 0; i < NA; i++) {
                float v = 0.f;
                if (j < NA) v = s_S[i * NA + j];
                else if (j < NA + NX) v = s_T1[i * NXP + (j - NA)];
                r[i] = v;
            }
            #pragma unroll
            for (int k = 0; k < NA; k++) {
                float piv = __shfl(r[k], k);
                float ip = 1.0f / piv;
                r[k] *= ip;
                #pragma unroll
                for (int i = 0; i < NA; i++) {
                    if (i == k) continue;
                    float f = __shfl(r[i], k);
                    r[i] = fmaf(-f, r[k], r[i]);
                }
            }
            if (j >= NA && j < NA + NX) {
                #pragma unroll
                for (int i = 0; i < NA; i++) s_Y[i * NX + (j - NA)] = r[i];
            }
        }
        __syncthreads();

        // ===== B8: qm = pm + Y^T innov ; qc = psd(pc - Y^T T1) — 1/lane =====
        if (tid < NX) {
            float acc = s_pm[tid];
            #pragma unroll
            for (int i = 0; i < NA; i++)
                acc = fmaf(s_Y[i * NX + tid], s_innov[i], acc);
            s_qm[tid] = acc;
            pack1_to(tid, acc, s_qmh);
        }
        if (tid < 528) {
            int i = iT, l = lT;
            float t_il = 0.f, t_li = 0.f;
            #pragma unroll
            for (int q = 0; q < NA; q++) {
                t_il = fmaf(s_Y[q * NX + i], s_T1[q * NXP + l], t_il);
                t_li = fmaf(s_Y[q * NX + l], s_T1[q * NXP + i], t_li);
            }
            if (i == l) {
                s_qc[i * NXP + i] = s_pc[i * NXP + i] - t_il + EPSV;
            } else {
                float v = 0.5f * ((s_pc[i * NXP + l] - t_il) + (s_pc[l * NXP + i] - t_li));
                s_qc[i * NXP + l] = v;
                s_qc[l * NXP + i] = v;
            }
        }
        __syncthreads();
    }

    // Epilogue: store final qm/qc (t = NT-1), coalesced
    {
        const size_t mLast = (size_t)(NT - 1) * NB + b;
        for (int s = tid; s < NX + NX * NX; s += 1024) {
            if (s < NX)
                __builtin_nontemporal_store(s_qm[s], out + qmO + mLast * NX + s);
            else {
                int o = s - NX, i = o >> 5, l = o & 31;
                __builtin_nontemporal_store(s_qc[i * NXP + l],
                                            out + qcO + mLast * NX * NX + o);
            }
        }
    }
}

// ---------------------------------------------------------------------------
extern "C" void kernel_launch(void* const* d_in, const int* in_sizes, int n_in,
                              void* d_out, int out_size, void* d_ws, size_t ws_size,
                              hipStream_t stream)
{
    const float* u    = (const float*)d_in[0];
    const float* a    = (const float*)d_in[1];
    const float* W1   = (const float*)d_in[2];
    const float* b1   = (const float*)d_in[3];
    const float* W2   = (const float*)d_in[4];
    const float* b2   = (const float*)d_in[5];
    const float* WA   = (const float*)d_in[6];
    const float* bA   = (const float*)d_in[7];
    const float* WB   = (const float*)d_in[8];
    const float* bB   = (const float*)d_in[9];
    const float* WC   = (const float*)d_in[10];
    const float* bC   = (const float*)d_in[11];
    const float* Wnx  = (const float*)d_in[12];
    const float* bnx  = (const float*)d_in[13];
    const float* Wna  = (const float*)d_in[14];
    const float* bna  = (const float*)d_in[15];
    const float* alph = (const float*)d_in[16];

    uint32* wsu = (uint32*)d_ws;
    float* out = (float*)d_out;

    auto pk = [&](const float* src, int O, int K, size_t dst_off, int LDP, int off) {
        int n = O * (K / 2);
        pack_half_off<<<(n + 255) / 256, 256, 0, stream>>>(src, wsu + dst_off, O, K, LDP, off);
    };
    pk(W1,  NH,      NX, OFF_W1, NH,  0);
    pk(W2,  NH,      NH, OFF_W2, NH,  0);
    pk(WA,  NX * NX, NH, OFF_H1, H1P, 0);
    pk(WB,  NX * NU, NH, OFF_H1, H1P, NX * NX);
    pk(Wnx, NX,      NH, OFF_H1, H1P, NX * NX + NX * NU);
    pk(WC,  NA * NX, NH, OFF_H2, H2P, 0);
    pk(Wna, NA,      NH, OFF_H2, H2P, NA * NX);

    pack_bias3<<<(H1O + 255) / 256, 256, 0, stream>>>(bA, NX * NX, bB, NX * NU, bnx, NX,
                                                      (float*)(wsu + OFF_B1));
    pack_bias3<<<(H2O + 255) / 256, 256, 0, stream>>>(bC, NA * NX, bna, NA, nullptr, 0,
                                                      (float*)(wsu + OFF_B2));

    kf_kernel<<<NB, 1024, 0, stream>>>(u, a, wsu, b1, b2, alph, out);
}